// Round 1
// 206.134 us; speedup vs baseline: 1.0025x; 1.0025x over previous
//
#include <hip/hip_runtime.h>
#include <math.h>

#define BB 8
#define SS 4096
#define HH 1024
#define KK 2048

// ---------------- Kernel 1: scores = sigmoid(hs @ w) ----------------
// One wave per token (4 waves / 256-thread block). Lane l reads float4
// index (l + 64j): each instruction covers 1 KB contiguous -> coalesced.
// Scores are staged into the OUTPUT buffer's mask half (not d_ws) so the
// kernel never touches the workspace allocation.
__global__ __launch_bounds__(256) void score_kernel(
    const float* __restrict__ hs, const float* __restrict__ w,
    float* __restrict__ scores) {
    const int lane = threadIdx.x & 63;
    const int wv = threadIdx.x >> 6;
    const int token = blockIdx.x * 4 + wv;

    const float4* w4 = (const float4*)w;                       // 4 KB, L1-resident
    const float4* h4 = (const float4*)(hs + (size_t)token * HH);

    double a0 = 0.0, a1 = 0.0, a2 = 0.0, a3 = 0.0;
#pragma unroll
    for (int j = 0; j < 4; ++j) {
        float4 h  = h4[lane + 64 * j];
        float4 wf = w4[lane + 64 * j];
        a0 += (double)h.x * (double)wf.x;
        a1 += (double)h.y * (double)wf.y;
        a2 += (double)h.z * (double)wf.z;
        a3 += (double)h.w * (double)wf.w;
    }
    double acc = (a0 + a1) + (a2 + a3);
#pragma unroll
    for (int off = 1; off < 64; off <<= 1)
        acc += __shfl_xor(acc, off);
    if (lane == 0)
        scores[token] = (float)(1.0 / (1.0 + exp(-acc)));
}

// ---------------- Kernel 2: per-row top-K selection ----------------
// One wave (64 threads) per batch row; whole row (4096 scores) held in
// registers as float4[16]. NOTE: `scores` aliases `maskout` (scores are
// staged in the mask half of the output buffer) -> NO __restrict__ here.
// All 16 row loads complete (feed the binary search) before any store,
// so the overwrite is safe within the single owning wave.
__global__ __launch_bounds__(64) void select_kernel(
    const float* scores, float* weights, float* maskout) {
    const int b = blockIdx.x;
    const int lane = threadIdx.x;
    const float4* row4 = (const float4*)(scores + b * SS);

    float4 f[16];
#pragma unroll
    for (int m = 0; m < 16; ++m) f[m] = row4[m * 64 + lane];

    // ---- binary search for threshold (30 iterations, register-only) ----
    unsigned lo = 0u, hi = 0x3F800001u;   // (0, 1.0f + 1ulp]: count(>=0)=S>=K, count(>=hi)=0<K
    while (hi - lo > 1u) {
        const unsigned mid = lo + ((hi - lo) >> 1);
        int c = 0;
#pragma unroll
        for (int m = 0; m < 16; ++m) {
            c += (__float_as_uint(f[m].x) >= mid);
            c += (__float_as_uint(f[m].y) >= mid);
            c += (__float_as_uint(f[m].z) >= mid);
            c += (__float_as_uint(f[m].w) >= mid);
        }
#pragma unroll
        for (int off = 32; off >= 1; off >>= 1) c += __shfl_xor(c, off);
        if (c >= KK) lo = mid; else hi = mid;
    }
    const unsigned thr = lo;

    // ---- count strictly-greater ----
    int cg = 0;
#pragma unroll
    for (int m = 0; m < 16; ++m) {
        cg += (__float_as_uint(f[m].x) > thr);
        cg += (__float_as_uint(f[m].y) > thr);
        cg += (__float_as_uint(f[m].z) > thr);
        cg += (__float_as_uint(f[m].w) > thr);
    }
#pragma unroll
    for (int off = 32; off >= 1; off >>= 1) cg += __shfl_xor(cg, off);
    const int need = KK - cg;   // ties to accept, lowest index first (>= 1)

    // ---- select + write, with index-ordered tie prefix ----
    float4* w4o = (float4*)(weights + b * SS);
    float4* m4o = (float4*)(maskout + b * SS);
    int base = 0;               // eq-count in groups < m (uniform)
#pragma unroll
    for (int m = 0; m < 16; ++m) {
        const float vals[4] = { f[m].x, f[m].y, f[m].z, f[m].w };
        unsigned u[4];
        int eq[4];
        int ec = 0;
#pragma unroll
        for (int c = 0; c < 4; ++c) {
            u[c] = __float_as_uint(vals[c]);
            eq[c] = (u[c] == thr) ? 1 : 0;
            ec += eq[c];
        }
        // inclusive prefix of ec over lanes
        int inc = ec;
#pragma unroll
        for (int off = 1; off < 64; off <<= 1) {
            int t = __shfl_up(inc, off);
            if (lane >= off) inc += t;
        }
        const int tot = __shfl(inc, 63);        // wave total (uniform)
        int r = base + inc - ec;                // eqs strictly before (m, lane, 0)
        float wout[4], mout[4];
#pragma unroll
        for (int c = 0; c < 4; ++c) {
            const bool sel = (u[c] > thr) || (eq[c] && r < need);
            r += eq[c];
            wout[c] = sel ? vals[c] : 0.0f;
            mout[c] = sel ? 1.0f : 0.0f;
        }
        base += tot;
        w4o[m * 64 + lane] = make_float4(wout[0], wout[1], wout[2], wout[3]);
        m4o[m * 64 + lane] = make_float4(mout[0], mout[1], mout[2], mout[3]);
    }
}

extern "C" void kernel_launch(void* const* d_in, const int* in_sizes, int n_in,
                              void* d_out, int out_size, void* d_ws, size_t ws_size,
                              hipStream_t stream) {
    const float* hs = (const float*)d_in[0];   // [B,S,H] fp32
    const float* w  = (const float*)d_in[1];   // [H] fp32
    float* out      = (float*)d_out;           // [B*S] weights ++ [B*S] mask
    float* weights  = out;
    float* mask     = out + (size_t)BB * SS;
    float* scores   = mask;                    // stage scores in mask half; d_ws UNUSED

    const int tokens = BB * SS;                // 32768
    score_kernel<<<tokens / 4, 256, 0, stream>>>(hs, w, scores);
    select_kernel<<<BB, 64, 0, stream>>>(scores, out, mask);
}